// Round 8
// baseline (122.907 us; speedup 1.0000x reference)
//
#include <hip/hip_runtime.h>
#include <hip/hip_bf16.h>

typedef __bf16 bf16x8 __attribute__((ext_vector_type(8)));
typedef float f32x4 __attribute__((ext_vector_type(4)));
typedef float f32x16 __attribute__((ext_vector_type(16)));

#define MFMA16 __builtin_amdgcn_mfma_f32_16x16x32_bf16
#define MFMA32 __builtin_amdgcn_mfma_f32_32x32x16_bf16

__device__ __forceinline__ unsigned short f2b(float f) {
  unsigned int u = __float_as_uint(f);
  u += 0x7FFFu + ((u >> 16) & 1u);
  return (unsigned short)(u >> 16);
}

__device__ __forceinline__ float b2f(unsigned short s) {
  return __uint_as_float(((unsigned)s) << 16);
}

union U128 {
  uint4 u;
  unsigned short s[8];
  bf16x8 b;
};

union BPack {
  __hip_bfloat162 h2;
  unsigned u;
};

__device__ __forceinline__ unsigned packbf(float a, float b) {
  BPack p;
  p.h2 = __float22bfloat162_rn(make_float2(a, b));
  return p.u;
}

// ---------------- projection via MFMA ----------------
// grid 512 = (b = blk&7, n0 = 64-tile). block 256 (4 waves).
// Y[96 pad][4096] = W[96x64] X[64x4096] per batch, bf16 MFMA 16x16x32.
// wq rows pre-scaled by log2(e) so attention uses native exp2.
// h stored BLOCKED: h_blk[b][n>>3][c][n&7] -> attention PV A-fragments
// are lane-contiguous 16B groups (coalesced).
__global__ __launch_bounds__(256, 2) void proj_kernel(
    const float* __restrict__ x, const float* __restrict__ wq,
    const float* __restrict__ wk, const float* __restrict__ wv_w,
    unsigned short* __restrict__ f_t, unsigned short* __restrict__ g_t,
    unsigned short* __restrict__ h_out) {
  __shared__ unsigned short xT[64 * 64];
  __shared__ unsigned short wT[96 * 72];

  const int tid = (int)threadIdx.x;
  const int wvp = tid >> 6;
  const int lane = tid & 63;
  const int b = (int)blockIdx.x & 7;
  const int n0 = ((int)blockIdx.x >> 3) << 6;

  // ---- stage xT: thread loads 16 c's for n=lane, packs, swizzled write ----
  {
    const float* xb = x + ((size_t)b << 18) + n0 + lane;
    const int c0 = wvp * 16;
    float xv[16];
#pragma unroll
    for (int cc = 0; cc < 16; ++cc) xv[cc] = xb[(size_t)(c0 + cc) << 12];
#pragma unroll
    for (int p = 0; p < 4; ++p) {
      const int c = c0 + 4 * p;
      uint2 d;
      d.x = packbf(xv[4 * p + 0], xv[4 * p + 1]);
      d.y = packbf(xv[4 * p + 2], xv[4 * p + 3]);
      const int g = c >> 3;
      const int idx = lane * 64 + (((g ^ (lane & 7)) << 3) | (((c >> 2) & 1) << 2));
      *(uint2*)&xT[idx] = d;
    }
  }
  // ---- stage wT (80 rows of 64, bf16); wq scaled by log2(e) ----
#pragma unroll
  for (int i = 0; i < 20; ++i) {
    const int idx = i * 256 + tid;
    const float wval = (idx < 512) ? wq[idx] * 1.44269504f
                     : (idx < 1024) ? wk[idx - 512]
                                    : wv_w[idx - 1024];
    wT[(idx >> 6) * 72 + (idx & 63)] = f2b(wval);
  }
  __syncthreads();

  // ---- compute ----
  const int t = lane & 15, q = lane >> 4;
  const int nloc = wvp * 16 + t;
  U128 Bf[2];
#pragma unroll
  for (int kp = 0; kp < 2; ++kp) {
    const int g = kp * 4 + q;
    Bf[kp].u = *(const uint4*)&xT[nloc * 64 + ((g ^ (nloc & 7)) << 3)];
  }
  const int nabs = n0 + nloc;
#pragma unroll
  for (int rt = 0; rt < 5; ++rt) {
    f32x4 acc = {0.f, 0.f, 0.f, 0.f};
#pragma unroll
    for (int kp = 0; kp < 2; ++kp) {
      U128 Af;
      Af.u = *(const uint4*)&wT[(rt * 16 + t) * 72 + ((kp * 4 + q) << 3)];
      acc = MFMA16(Af.b, Bf[kp].b, acc, 0, 0, 0);
    }
#pragma unroll
    for (int reg = 0; reg < 4; ++reg) {
      const int r = rt * 16 + 4 * q + reg;
      const unsigned short v = f2b(acc[reg]);
      if (r < 8)
        f_t[((size_t)((b << 12) + nabs) << 3) + r] = v;
      else if (r < 16)
        g_t[((size_t)((b << 12) + nabs) << 3) + (r - 8)] = v;
      else
        h_out[((size_t)b << 18) + ((size_t)(nabs >> 3) << 9) +
              ((r - 16) << 3) + (nabs & 7)] = v;
    }
  }
}

// ---------------- flash attention: m64 per wave ----------------
// grid 512 = (b = blk&7, m64-tile). block 512 (8 waves, 2 blocks/CU).
// Wave w: TWO m32-tiles (G_A=m64..+31, G_B=+32..63) x n-eighth (16 iters
// of 32 n). Each H/F fragment loaded once, used for both m-tiles -> L1
// traffic halved vs m32/wave. Per iter: 2 score MFMA32, 2x(16 exp2 + pack
// + shfl_xor(32) C->B transform + 4 PV MFMA32). launch_bounds(512,4) gives
// a 128-VGPR budget so the score regs stay in VGPRs (no accvgpr churn).
__global__ __launch_bounds__(512, 4) void attn_kernel(
    const unsigned short* __restrict__ f_t, const unsigned short* __restrict__ g_t,
    const unsigned short* __restrict__ h, const float* __restrict__ x,
    const float* __restrict__ gamma, float* __restrict__ out) {
  __shared__ unsigned short Opart[8][64][66];  // [wave][m][c] bf16, 67.6 KB
  __shared__ float lred[8][64];
  __shared__ float lsum[64];

  const int tid = (int)threadIdx.x;
  const int wave = tid >> 6;
  const int lane = tid & 63;
  const int ml = lane & 31;
  const int hh = lane >> 5;

  const int b = (int)blockIdx.x & 7;
  const int m64 = ((int)blockIdx.x >> 3) << 6;

  const unsigned short* fb = f_t + ((size_t)b << 15);
  const unsigned short* hb = h + ((size_t)b << 18);  // blocked layout

  U128 GA, GB;
  GA.u = make_uint4(0u, 0u, 0u, 0u);
  GB.u = make_uint4(0u, 0u, 0u, 0u);
  if (hh == 0) {
    GA.u = *(const uint4*)(g_t + ((size_t)((b << 12) + m64 + ml) << 3));
    GB.u = *(const uint4*)(g_t + ((size_t)((b << 12) + m64 + 32 + ml) << 3));
  }

  f32x16 OA0 = {}, OA1 = {}, OB0 = {}, OB1 = {};
  float lpA = 0.f, lpB = 0.f;

  const int nbase = wave << 9;  // 512 n per wave

  for (int it = 0; it < 16; ++it) {
    const int n32 = nbase + (it << 5);

    // H A-fragments (blocked layout): shared by both m-tiles
    U128 H00, H01, H10, H11;
    {
      const unsigned short* hg = hb + ((n32 >> 3) << 9) + (hh << 9) + (ml << 3);
      H00.u = *(const uint4*)(hg);                // ct0 kt0
      H10.u = *(const uint4*)(hg + 256);          // ct1 kt0
      H01.u = *(const uint4*)(hg + 1024);         // ct0 kt1
      H11.u = *(const uint4*)(hg + 1024 + 256);   // ct1 kt1
    }
    U128 F;
    F.u = *(const uint4*)(fb + ((size_t)(n32 + ml) << 3));

    const f32x16 z = {};
    f32x16 SA = MFMA32(F.b, GA.b, z, 0, 0, 0);
    f32x16 SB = MFMA32(F.b, GB.b, z, 0, 0, 0);

    // ---- m-tile A ----
#pragma unroll
    for (int kt = 0; kt < 2; ++kt) {
      float e[8];
#pragma unroll
      for (int r = 0; r < 8; ++r) e[r] = __builtin_amdgcn_exp2f(SA[8 * kt + r]);
#pragma unroll
      for (int r = 0; r < 8; ++r) lpA += e[r];
      const unsigned A0 = packbf(e[0], e[1]);
      const unsigned A1 = packbf(e[2], e[3]);
      const unsigned B0 = packbf(e[4], e[5]);
      const unsigned B1 = packbf(e[6], e[7]);
      const unsigned s0 = hh ? A0 : B0;
      const unsigned s1 = hh ? A1 : B1;
      const unsigned r0 = (unsigned)__shfl_xor((int)s0, 32, 64);
      const unsigned r1 = (unsigned)__shfl_xor((int)s1, 32, 64);
      U128 P;
      P.u.x = hh ? r0 : A0;
      P.u.y = hh ? r1 : A1;
      P.u.z = hh ? B0 : r0;
      P.u.w = hh ? B1 : r1;
      if (kt == 0) {
        OA0 = MFMA32(H00.b, P.b, OA0, 0, 0, 0);
        OA1 = MFMA32(H10.b, P.b, OA1, 0, 0, 0);
      } else {
        OA0 = MFMA32(H01.b, P.b, OA0, 0, 0, 0);
        OA1 = MFMA32(H11.b, P.b, OA1, 0, 0, 0);
      }
    }

    // ---- m-tile B ----
#pragma unroll
    for (int kt = 0; kt < 2; ++kt) {
      float e[8];
#pragma unroll
      for (int r = 0; r < 8; ++r) e[r] = __builtin_amdgcn_exp2f(SB[8 * kt + r]);
#pragma unroll
      for (int r = 0; r < 8; ++r) lpB += e[r];
      const unsigned A0 = packbf(e[0], e[1]);
      const unsigned A1 = packbf(e[2], e[3]);
      const unsigned B0 = packbf(e[4], e[5]);
      const unsigned B1 = packbf(e[6], e[7]);
      const unsigned s0 = hh ? A0 : B0;
      const unsigned s1 = hh ? A1 : B1;
      const unsigned r0 = (unsigned)__shfl_xor((int)s0, 32, 64);
      const unsigned r1 = (unsigned)__shfl_xor((int)s1, 32, 64);
      U128 P;
      P.u.x = hh ? r0 : A0;
      P.u.y = hh ? r1 : A1;
      P.u.z = hh ? B0 : r0;
      P.u.w = hh ? B1 : r1;
      if (kt == 0) {
        OB0 = MFMA32(H00.b, P.b, OB0, 0, 0, 0);
        OB1 = MFMA32(H10.b, P.b, OB1, 0, 0, 0);
      } else {
        OB0 = MFMA32(H01.b, P.b, OB0, 0, 0, 0);
        OB1 = MFMA32(H11.b, P.b, OB1, 0, 0, 0);
      }
    }
  }

  // wave-local denominators, stash partials (bf16 pairs)
  lpA += __shfl_xor(lpA, 32, 64);
  lpB += __shfl_xor(lpB, 32, 64);
  if (hh == 0) {
    lred[wave][ml] = lpA;
    lred[wave][32 + ml] = lpB;
  }
#pragma unroll
  for (int r = 0; r < 8; ++r) {
    const int c0 = ((2 * r) & 3) + 8 * (r >> 1) + 4 * hh;
    *(unsigned*)&Opart[wave][ml][c0] = packbf(OA0[2 * r], OA0[2 * r + 1]);
    *(unsigned*)&Opart[wave][ml][c0 + 32] = packbf(OA1[2 * r], OA1[2 * r + 1]);
    *(unsigned*)&Opart[wave][32 + ml][c0] = packbf(OB0[2 * r], OB0[2 * r + 1]);
    *(unsigned*)&Opart[wave][32 + ml][c0 + 32] = packbf(OB1[2 * r], OB1[2 * r + 1]);
  }
  __syncthreads();
  if (tid < 64) {
    float s = 0.f;
#pragma unroll
    for (int w = 0; w < 8; ++w) s += lred[w][tid];
    lsum[tid] = s;
  }
  __syncthreads();

  // epilogue: thread owns c = tid>>3, m = (tid&7)*8 .. +8
  const int c = tid >> 3;
  const int m0l = (tid & 7) << 3;
  const float gam = gamma[0];
  float a[8];
#pragma unroll
  for (int j = 0; j < 8; ++j) a[j] = 0.f;
#pragma unroll
  for (int w = 0; w < 8; ++w)
#pragma unroll
    for (int j = 0; j < 8; ++j) a[j] += b2f(Opart[w][m0l + j][c]);

  const f32x4 l0 = *(const f32x4*)&lsum[m0l];
  const f32x4 l1 = *(const f32x4*)&lsum[m0l + 4];
  const size_t oi = (((size_t)b * 64 + c) << 12) + m64 + m0l;
  f32x4 xo0 = *(const f32x4*)(x + oi);
  f32x4 xo1 = *(const f32x4*)(x + oi + 4);
#pragma unroll
  for (int j = 0; j < 4; ++j) {
    xo0[j] += gam / l0[j] * a[j];
    xo1[j] += gam / l1[j] * a[j + 4];
  }
  *(f32x4*)(out + oi) = xo0;
  *(f32x4*)(out + oi + 4) = xo1;
}

extern "C" void kernel_launch(void* const* d_in, const int* in_sizes, int n_in,
                              void* d_out, int out_size, void* d_ws, size_t ws_size,
                              hipStream_t stream) {
  (void)in_sizes; (void)n_in; (void)out_size; (void)ws_size;
  const float* x = (const float*)d_in[0];
  const float* wq = (const float*)d_in[1];
  const float* wk = (const float*)d_in[2];
  const float* wv = (const float*)d_in[3];
  const float* gamma = (const float*)d_in[4];
  float* out = (float*)d_out;

  // workspace: f_t [8][4096][8] bf16, g_t same, h_blk [8][512][64][8] bf16
  unsigned short* f_t = (unsigned short*)d_ws;
  unsigned short* g_t = f_t + (size_t)8 * 4096 * 8;
  unsigned short* h = g_t + (size_t)8 * 4096 * 8;

  proj_kernel<<<512, 256, 0, stream>>>(x, wq, wk, wv, f_t, g_t, h);
  attn_kernel<<<512, 512, 0, stream>>>(f_t, g_t, h, x, gamma, out);
}

// Round 9
// 108.445 us; speedup vs baseline: 1.1334x; 1.1334x over previous
//
#include <hip/hip_runtime.h>
#include <hip/hip_bf16.h>

typedef __bf16 bf16x8 __attribute__((ext_vector_type(8)));
typedef float f32x4 __attribute__((ext_vector_type(4)));
typedef float f32x16 __attribute__((ext_vector_type(16)));

#define MFMA16 __builtin_amdgcn_mfma_f32_16x16x32_bf16
#define MFMA32 __builtin_amdgcn_mfma_f32_32x32x16_bf16

__device__ __forceinline__ unsigned short f2b(float f) {
  unsigned int u = __float_as_uint(f);
  u += 0x7FFFu + ((u >> 16) & 1u);
  return (unsigned short)(u >> 16);
}

__device__ __forceinline__ float b2f(unsigned short s) {
  return __uint_as_float(((unsigned)s) << 16);
}

union U128 {
  uint4 u;
  unsigned short s[8];
  bf16x8 b;
};

union BPack {
  __hip_bfloat162 h2;
  unsigned u;
};

__device__ __forceinline__ unsigned packbf(float a, float b) {
  BPack p;
  p.h2 = __float22bfloat162_rn(make_float2(a, b));
  return p.u;
}

// ---------------- projection via MFMA ----------------
// grid 512 = (b = blk&7, n0 = 64-tile). block 256 (4 waves).
// Y[96 pad][4096] = W[96x64] X[64x4096] per batch, bf16 MFMA 16x16x32.
// wq rows pre-scaled by log2(e) so attention uses native exp2.
// h stored BLOCKED: h_blk[b][n>>3][c][n&7] -> attention PV A-fragments
// are lane-contiguous 16B groups (coalesced).
__global__ __launch_bounds__(256, 2) void proj_kernel(
    const float* __restrict__ x, const float* __restrict__ wq,
    const float* __restrict__ wk, const float* __restrict__ wv_w,
    unsigned short* __restrict__ f_t, unsigned short* __restrict__ g_t,
    unsigned short* __restrict__ h_out) {
  __shared__ unsigned short xT[64 * 64];
  __shared__ unsigned short wT[96 * 72];

  const int tid = (int)threadIdx.x;
  const int wvp = tid >> 6;
  const int lane = tid & 63;
  const int b = (int)blockIdx.x & 7;
  const int n0 = ((int)blockIdx.x >> 3) << 6;

  // ---- stage xT: thread loads 16 c's for n=lane, packs, swizzled write ----
  {
    const float* xb = x + ((size_t)b << 18) + n0 + lane;
    const int c0 = wvp * 16;
    float xv[16];
#pragma unroll
    for (int cc = 0; cc < 16; ++cc) xv[cc] = xb[(size_t)(c0 + cc) << 12];
#pragma unroll
    for (int p = 0; p < 4; ++p) {
      const int c = c0 + 4 * p;
      uint2 d;
      d.x = packbf(xv[4 * p + 0], xv[4 * p + 1]);
      d.y = packbf(xv[4 * p + 2], xv[4 * p + 3]);
      const int g = c >> 3;
      const int idx = lane * 64 + (((g ^ (lane & 7)) << 3) | (((c >> 2) & 1) << 2));
      *(uint2*)&xT[idx] = d;
    }
  }
  // ---- stage wT (80 rows of 64, bf16); wq scaled by log2(e) ----
#pragma unroll
  for (int i = 0; i < 20; ++i) {
    const int idx = i * 256 + tid;
    const float wval = (idx < 512) ? wq[idx] * 1.44269504f
                     : (idx < 1024) ? wk[idx - 512]
                                    : wv_w[idx - 1024];
    wT[(idx >> 6) * 72 + (idx & 63)] = f2b(wval);
  }
  __syncthreads();

  // ---- compute ----
  const int t = lane & 15, q = lane >> 4;
  const int nloc = wvp * 16 + t;
  U128 Bf[2];
#pragma unroll
  for (int kp = 0; kp < 2; ++kp) {
    const int g = kp * 4 + q;
    Bf[kp].u = *(const uint4*)&xT[nloc * 64 + ((g ^ (nloc & 7)) << 3)];
  }
  const int nabs = n0 + nloc;
#pragma unroll
  for (int rt = 0; rt < 5; ++rt) {
    f32x4 acc = {0.f, 0.f, 0.f, 0.f};
#pragma unroll
    for (int kp = 0; kp < 2; ++kp) {
      U128 Af;
      Af.u = *(const uint4*)&wT[(rt * 16 + t) * 72 + ((kp * 4 + q) << 3)];
      acc = MFMA16(Af.b, Bf[kp].b, acc, 0, 0, 0);
    }
#pragma unroll
    for (int reg = 0; reg < 4; ++reg) {
      const int r = rt * 16 + 4 * q + reg;
      const unsigned short v = f2b(acc[reg]);
      if (r < 8)
        f_t[((size_t)((b << 12) + nabs) << 3) + r] = v;
      else if (r < 16)
        g_t[((size_t)((b << 12) + nabs) << 3) + (r - 8)] = v;
      else
        h_out[((size_t)b << 18) + ((size_t)(nabs >> 3) << 9) +
              ((r - 16) << 3) + (nabs & 7)] = v;
    }
  }
}

// ---------------- flash attention: independent waves (R7) + H prefetch ------
// grid 1024 = (b = blk&7, m32-tile). block 256 (4 waves). Wave w: all 64 c x
// 32 m, n-quarter in 32-tiles. Per tile: score MFMA32 (K 8->16, zero G half),
// 16 v_exp (exp2), C->B transform via shfl_xor(32) on packed bf16 pairs,
// 4 PV MFMA32. H AND F both double-buffered (prefetch it+1 before compute)
// so L2 latency hides under the exp/pack chain. launch_bounds(256,4): grid
// binds occupancy at 4 blocks/CU anyway; wider VGPR budget avoids AGPR churn.
__global__ __launch_bounds__(256, 4) void attn_kernel(
    const unsigned short* __restrict__ f_t, const unsigned short* __restrict__ g_t,
    const unsigned short* __restrict__ h, const float* __restrict__ x,
    const float* __restrict__ gamma, float* __restrict__ out) {
  __shared__ unsigned short Opart[4][32][66];  // [wave][m][c], bf16, 16.9 KB
  __shared__ float lred[4][32];
  __shared__ float lsum[32];

  const int tid = (int)threadIdx.x;
  const int wave = tid >> 6;
  const int lane = tid & 63;
  const int ml = lane & 31;
  const int hh = lane >> 5;

  const int b = (int)blockIdx.x & 7;
  const int m32 = ((int)blockIdx.x >> 3) << 5;

  const unsigned short* fb = f_t + ((size_t)b << 15);
  const unsigned short* hb = h + ((size_t)b << 18);  // blocked layout

  U128 G;
  G.u = make_uint4(0u, 0u, 0u, 0u);
  if (hh == 0) G.u = *(const uint4*)(g_t + ((size_t)((b << 12) + m32 + ml) << 3));

  f32x16 O0 = {}, O1 = {};
  float lpa = 0.f, lpb = 0.f;

  const int nbase = wave << 10;

  // pointer-increment bases
  const unsigned short* fp = fb + ((size_t)(nbase + ml) << 3);      // +256/iter
  const unsigned short* hp = hb + ((nbase >> 3) << 9) + (hh << 9) + (ml << 3);  // +2048/iter

  // prologue: tile 0 fragments
  U128 F, Fn, Ha[4], Hn[4];
  F.u = *(const uint4*)(fp);
  Ha[0].u = *(const uint4*)(hp);                 // ct0 kt0
  Ha[1].u = *(const uint4*)(hp + 256);           // ct1 kt0
  Ha[2].u = *(const uint4*)(hp + 1024);          // ct0 kt1
  Ha[3].u = *(const uint4*)(hp + 1024 + 256);    // ct1 kt1

  for (int it = 0; it < 32; ++it) {
    // ---- prefetch tile it+1 (clamped on last iter; values unused) ----
    const int adv = (it < 31) ? 1 : 0;
    Fn.u = *(const uint4*)(fp + adv * 256);
    const unsigned short* hq = hp + adv * 2048;
    Hn[0].u = *(const uint4*)(hq);
    Hn[1].u = *(const uint4*)(hq + 256);
    Hn[2].u = *(const uint4*)(hq + 1024);
    Hn[3].u = *(const uint4*)(hq + 1024 + 256);
    fp += 256;
    hp += 2048;

    const f32x16 z = {};
    f32x16 S = MFMA32(F.b, G.b, z, 0, 0, 0);

    float e[16];
#pragma unroll
    for (int r = 0; r < 16; ++r) e[r] = __builtin_amdgcn_exp2f(S[r]);
#pragma unroll
    for (int r = 0; r < 8; ++r) {
      lpa += e[2 * r];
      lpb += e[2 * r + 1];
    }

    // C->B transform: per kt, exchange packed bf16 pairs with lane^32
#pragma unroll
    for (int kt = 0; kt < 2; ++kt) {
      const unsigned A0 = packbf(e[8 * kt + 0], e[8 * kt + 1]);
      const unsigned A1 = packbf(e[8 * kt + 2], e[8 * kt + 3]);
      const unsigned B0 = packbf(e[8 * kt + 4], e[8 * kt + 5]);
      const unsigned B1 = packbf(e[8 * kt + 6], e[8 * kt + 7]);
      const unsigned s0 = hh ? A0 : B0;
      const unsigned s1 = hh ? A1 : B1;
      const unsigned r0 = (unsigned)__shfl_xor((int)s0, 32, 64);
      const unsigned r1 = (unsigned)__shfl_xor((int)s1, 32, 64);
      U128 P;
      P.u.x = hh ? r0 : A0;
      P.u.y = hh ? r1 : A1;
      P.u.z = hh ? B0 : r0;
      P.u.w = hh ? B1 : r1;
      if (kt == 0) {
        O0 = MFMA32(Ha[0].b, P.b, O0, 0, 0, 0);
        O1 = MFMA32(Ha[1].b, P.b, O1, 0, 0, 0);
      } else {
        O0 = MFMA32(Ha[2].b, P.b, O0, 0, 0, 0);
        O1 = MFMA32(Ha[3].b, P.b, O1, 0, 0, 0);
      }
    }

    // rotate
    F = Fn;
#pragma unroll
    for (int k = 0; k < 4; ++k) Ha[k] = Hn[k];
  }

  // wave-local denominator (both halves), then stash partials (bf16 pairs)
  float lp = lpa + lpb;
  lp += __shfl_xor(lp, 32, 64);
  if (hh == 0) lred[wave][ml] = lp;
#pragma unroll
  for (int r = 0; r < 8; ++r) {
    const int c0 = ((2 * r) & 3) + 8 * (r >> 1) + 4 * hh;
    *(unsigned*)&Opart[wave][ml][c0] = packbf(O0[2 * r], O0[2 * r + 1]);
    *(unsigned*)&Opart[wave][ml][c0 + 32] = packbf(O1[2 * r], O1[2 * r + 1]);
  }
  __syncthreads();
  if (tid < 32)
    lsum[tid] = (lred[0][tid] + lred[1][tid]) + (lred[2][tid] + lred[3][tid]);
  __syncthreads();

  // epilogue: thread owns c = tid>>2, m = (tid&3)*8 .. +8 (vectorized global)
  const int c = tid >> 2;
  const int m0l = (tid & 3) << 3;
  const float gam = gamma[0];
  float a[8];
#pragma unroll
  for (int j = 0; j < 8; ++j) a[j] = 0.f;
#pragma unroll
  for (int w = 0; w < 4; ++w)
#pragma unroll
    for (int j = 0; j < 8; ++j) a[j] += b2f(Opart[w][m0l + j][c]);

  const f32x4 l0 = *(const f32x4*)&lsum[m0l];
  const f32x4 l1 = *(const f32x4*)&lsum[m0l + 4];
  const size_t oi = (((size_t)b * 64 + c) << 12) + m32 + m0l;
  f32x4 xo0 = *(const f32x4*)(x + oi);
  f32x4 xo1 = *(const f32x4*)(x + oi + 4);
#pragma unroll
  for (int j = 0; j < 4; ++j) {
    xo0[j] += gam / l0[j] * a[j];
    xo1[j] += gam / l1[j] * a[j + 4];
  }
  *(f32x4*)(out + oi) = xo0;
  *(f32x4*)(out + oi + 4) = xo1;
}

extern "C" void kernel_launch(void* const* d_in, const int* in_sizes, int n_in,
                              void* d_out, int out_size, void* d_ws, size_t ws_size,
                              hipStream_t stream) {
  (void)in_sizes; (void)n_in; (void)out_size; (void)ws_size;
  const float* x = (const float*)d_in[0];
  const float* wq = (const float*)d_in[1];
  const float* wk = (const float*)d_in[2];
  const float* wv = (const float*)d_in[3];
  const float* gamma = (const float*)d_in[4];
  float* out = (float*)d_out;

  // workspace: f_t [8][4096][8] bf16, g_t same, h_blk [8][512][64][8] bf16
  unsigned short* f_t = (unsigned short*)d_ws;
  unsigned short* g_t = f_t + (size_t)8 * 4096 * 8;
  unsigned short* h = g_t + (size_t)8 * 4096 * 8;

  proj_kernel<<<512, 256, 0, stream>>>(x, wq, wk, wv, f_t, g_t, h);
  attn_kernel<<<1024, 256, 0, stream>>>(f_t, g_t, h, x, gamma, out);
}